// Round 7
// baseline (79.944 us; speedup 1.0000x reference)
//
#include <hip/hip_runtime.h>
#include <stdint.h>

// Problem dims
#define NB   4096   // batch rows (M)
#define KD   2048   // IN + S   (K)
#define ND   4096   // 4*S      (N, reordered: n -> gate=(n>>4)&3, s=(n>>6)*16+(n&15))
#define SD   1024   // state size

// GEMM tile (256x256, 8 waves = 2M x 4N, SGB-interleaved MFMA||ds_read)
#define BM   256
#define BN   256
#define BK   64
#define NKT  (KD / BK)   // 32 K-tiles

using f32x4  = __attribute__((ext_vector_type(4))) float;
using bf16x8 = __attribute__((ext_vector_type(8))) short;

typedef const __attribute__((address_space(1))) uint32_t* gas_u32;
typedef __attribute__((address_space(3))) uint32_t* las_u32;

__device__ __forceinline__ unsigned short f2bf(float f) {
    union { float f; uint32_t u; } c; c.f = f;
    uint32_t u = c.u;
    uint32_t r = (u + 0x7fffu + ((u >> 16) & 1u)) >> 16;  // RNE
    return (unsigned short)r;
}

__device__ __forceinline__ void async_load16(const void* gsrc, void* ldst) {
    __builtin_amdgcn_global_load_lds((gas_u32)gsrc, (las_u32)ldst, 16, 0, 0);
}

__device__ __forceinline__ float frcp(float x) { return __builtin_amdgcn_rcpf(x); }
__device__ __forceinline__ float sigm(float x) { return frcp(1.f + __expf(-x)); }
__device__ __forceinline__ float tanh_fast(float x) {
    return 1.f - 2.f * frcp(1.f + __expf(2.f * x));   // inf-safe
}

// ---------------------------------------------------------------------------
// Pack: fp32 -> bf16, X=[input|old_h]; W rows reordered so GEMM column
// n maps to weights row  gate*SD + (n>>6)*16 + (n&15),  gate=(n>>4)&3.
// ---------------------------------------------------------------------------
__global__ void pack_kernel(const float* __restrict__ input,
                            const float* __restrict__ old_h,
                            const float* __restrict__ weights,
                            const float* __restrict__ bias,
                            unsigned short* __restrict__ Xb,
                            unsigned short* __restrict__ Wb,
                            float* __restrict__ biasR) {
    const int XCH = NB * (KD / 4);
    const int WCH = ND * (KD / 4);
    const int BCH = ND / 4;
    const int total = XCH + WCH + BCH;
    for (int c = blockIdx.x * blockDim.x + threadIdx.x; c < total;
         c += gridDim.x * blockDim.x) {
        if (c < XCH) {
            int b  = c >> 9;
            int k  = (c & 511) << 2;
            const float* src = (k < 1024) ? (input + (size_t)b * 1024 + k)
                                          : (old_h + (size_t)b * 1024 + (k - 1024));
            float4 v = *reinterpret_cast<const float4*>(src);
            ushort4 o;
            o.x = f2bf(v.x); o.y = f2bf(v.y); o.z = f2bf(v.z); o.w = f2bf(v.w);
            *reinterpret_cast<ushort4*>(Xb + (size_t)b * KD + k) = o;
        } else if (c < XCH + WCH) {
            int cc = c - XCH;
            int n  = cc >> 9;
            int k  = (cc & 511) << 2;
            int srow = ((n >> 4) & 3) * SD + ((n >> 6) * 16 + (n & 15));
            float4 v = *reinterpret_cast<const float4*>(weights + (size_t)srow * KD + k);
            ushort4 o;
            o.x = f2bf(v.x); o.y = f2bf(v.y); o.z = f2bf(v.z); o.w = f2bf(v.w);
            *reinterpret_cast<ushort4*>(Wb + (size_t)n * KD + k) = o;
        } else {
            int n4 = (c - XCH - WCH) << 2;
            #pragma unroll
            for (int t = 0; t < 4; ++t) {
                int n = n4 + t;
                biasR[n] = bias[((n >> 4) & 3) * SD + ((n >> 6) * 16 + (n & 15))];
            }
        }
    }
}

// ---------------------------------------------------------------------------
// 256x256 GEMM + fused LSTM epilogue; 4 phases/K-tile, 1 barrier/phase.
// Dataflow = R5-benched (MMA consumes OLD frags, loads AFTER in program
// order); sched_group_barrier pins an MFMA||ds_read emission interleave so
// the LDS pipe drains UNDER the matrix pipe (R5 profile: serialized).
//   q0: [DS1,MFMA4]x4            reads ba<-B(t).nq1
//   q1: [VM4][MFMA4,DS2]x4       reads a<-A(t).mq1;    stage B(t+2) h0+h1
//   q2: [VM4][MFMA4,DS1]x4 (jk)  reads bm<-B(t+1).nq0; stage A(t+2) h0+h1
//   q3: [MFMA4,DS2]x4            reads a<-A(t+1).mq0
// Gate: lgkm0 before every head barrier (cross-wave region guarantee);
// vmcnt(4) at q2 head only: outstanding there = [A(t+1)x4 (q2 of t-1),
// B(t+2)x4 (q1 of t)] = 8 -> drain 4 = tile t+1 fully landed before its
// q2/q3 reads. Stage legality: B(t) last read q0(t) -> staged q1(t) (1
// barrier apart); A(t) last read q1(t) -> staged q2(t). Prologue: 16 loads,
// vmcnt(8) -> tile0 landed; first gate sees 12 -> drains tile1. OK.
// ---------------------------------------------------------------------------
#define SEG(DB, AB, HALF) (((((DB) * 2 + (AB)) * 2) + (HALF)) * 8192)

#define SBAR   __builtin_amdgcn_s_barrier()
#define SFENCE __builtin_amdgcn_sched_barrier(0)
#define SGB(M, N)  __builtin_amdgcn_sched_group_barrier((M), (N), 0)
#define ASM_LGKM0  asm volatile("s_waitcnt lgkmcnt(0)" ::: "memory")
#define ASM_VMCNT4 asm volatile("s_waitcnt vmcnt(4)" ::: "memory")
#define ASM_VMCNT8 asm volatile("s_waitcnt vmcnt(8)" ::: "memory")

__launch_bounds__(512, 2)
__global__ void lstm_gemm(const unsigned short* __restrict__ Xb,
                          const unsigned short* __restrict__ Wb,
                          const float* __restrict__ biasR,
                          const float* __restrict__ old_cell,
                          float* __restrict__ new_h,
                          float* __restrict__ new_cell) {
    __shared__ unsigned short lds[65536];   // 128 KiB

    const int tid  = threadIdx.x;
    const int lane = tid & 63;
    const int wid  = tid >> 6;       // 0..7
    const int wm   = wid >> 2;       // 0..1  (M half owner)
    const int wn   = wid & 3;        // 0..3  (N quarter owner)
    const int l15  = lane & 15;
    const int krow = lane >> 4;      // 0..3

    // XCD-aware bijective swizzle (256 blocks, 8 XCDs)
    const int wg    = blockIdx.x;
    const int swz   = (wg & 7) * 32 + (wg >> 3);
    const int mblk  = swz >> 4;
    const int nblk  = swz & 15;
    const int rbase = mblk * BM;
    const int nbase = nblk * BN;

    // staging per-thread constants: half-tile = 128 rows x 64 cols = 1024 chunks
    const int c0 = tid, c1 = tid + 512;
    const int srow0 = c0 >> 3, sk0 = ((c0 & 7) ^ (srow0 & 7)) * 8;
    const int srow1 = c1 >> 3, sk1 = ((c1 & 7) ^ (srow1 & 7)) * 8;

    f32x4  acc[8][4] = {};
    bf16x8 a[4][2];        // current A quadrant (renamed in place, i-ordered)
    bf16x8 bm[2][2];       // B wave-panel cols 0-31 (nq=0)
    bf16x8 ba[2][2];       // B wave-panel cols 32-63 (nq=1)

#define STAGE(PTR, TB, KT, DB, AB, HALF) do {                                   \
        async_load16((PTR) + (size_t)((TB) + (HALF) * 128 + srow0) * KD +       \
                         (KT) * BK + sk0,                                       \
                     lds + SEG(DB, AB, HALF) + c0 * 8);                         \
        async_load16((PTR) + (size_t)((TB) + (HALF) * 128 + srow1) * KD +       \
                         (KT) * BK + sk1,                                       \
                     lds + SEG(DB, AB, HALF) + c1 * 8);                         \
    } while (0)

#define LOAD_A(DB, MQ) do {                                                     \
        const unsigned short* base_ = lds + SEG(DB, 0, 0) + wm * 8192;          \
        _Pragma("unroll") for (int i_ = 0; i_ < 4; ++i_)                        \
        _Pragma("unroll") for (int kk_ = 0; kk_ < 2; ++kk_) {                   \
            int r_ = (MQ) * 64 + i_ * 16 + l15;                                 \
            int s_ = kk_ * 4 + krow;                                            \
            a[i_][kk_] = *reinterpret_cast<const bf16x8*>(                      \
                base_ + r_ * 64 + ((s_ ^ (r_ & 7)) * 8));                       \
        }                                                                       \
    } while (0)

#define LOAD_B_TO(DST, DB, NQ) do {                                             \
        const unsigned short* base_ = lds + SEG(DB, 1, 0) + (wn >> 1) * 8192;   \
        _Pragma("unroll") for (int j_ = 0; j_ < 2; ++j_)                        \
        _Pragma("unroll") for (int kk_ = 0; kk_ < 2; ++kk_) {                   \
            int r_ = (wn & 1) * 64 + ((NQ) * 2 + j_) * 16 + l15;                \
            int s_ = kk_ * 4 + krow;                                            \
            DST[j_][kk_] = *reinterpret_cast<const bf16x8*>(                    \
                base_ + r_ * 64 + ((s_ ^ (r_ & 7)) * 8));                       \
        }                                                                       \
    } while (0)

    // i-outer MFMA order (a[i] dies after its 4-MFMA group -> WAR-friendly
    // with i-ordered LOAD_A interleave)
#define MMA_Q(MQ, NQH, BB) do {                                                 \
        _Pragma("unroll") for (int i_ = 0; i_ < 4; ++i_)                        \
        _Pragma("unroll") for (int j_ = 0; j_ < 2; ++j_)                        \
        _Pragma("unroll") for (int kk_ = 0; kk_ < 2; ++kk_)                     \
            acc[(MQ) * 4 + i_][(NQH) * 2 + j_] =                                \
                __builtin_amdgcn_mfma_f32_16x16x32_bf16(                        \
                    a[i_][kk_], BB[j_][kk_],                                    \
                    acc[(MQ) * 4 + i_][(NQH) * 2 + j_], 0, 0, 0);               \
    } while (0)

    // jk-outer MFMA order (bm[j][kk] dies after its 4-MFMA group, for q2)
#define MMA_Q_JK(MQ, NQH, BB) do {                                              \
        _Pragma("unroll") for (int j_ = 0; j_ < 2; ++j_)                        \
        _Pragma("unroll") for (int kk_ = 0; kk_ < 2; ++kk_)                     \
        _Pragma("unroll") for (int i_ = 0; i_ < 4; ++i_)                        \
            acc[(MQ) * 4 + i_][(NQH) * 2 + j_] =                                \
                __builtin_amdgcn_mfma_f32_16x16x32_bf16(                        \
                    a[i_][kk_], BB[j_][kk_],                                    \
                    acc[(MQ) * 4 + i_][(NQH) * 2 + j_], 0, 0, 0);               \
    } while (0)

#define PH_HEAD   SFENCE; ASM_LGKM0; SBAR; SFENCE; __builtin_amdgcn_s_setprio(1)
#define PH_HEADV  SFENCE; ASM_LGKM0; ASM_VMCNT4; SBAR; SFENCE; __builtin_amdgcn_s_setprio(1)
#define PRIO0     __builtin_amdgcn_s_setprio(0)

    // SGB emission pins (region bounded by PH_* SFENCEs)
#define SGB_Q0  _Pragma("unroll") for (int g_ = 0; g_ < 4; ++g_) { SGB(0x100, 1); SGB(0x8, 4); }
#define SGB_Q1  SGB(0x70, 4);                                                   \
                _Pragma("unroll") for (int g_ = 0; g_ < 4; ++g_) { SGB(0x8, 4); SGB(0x100, 2); }
#define SGB_Q2  SGB(0x70, 4);                                                   \
                _Pragma("unroll") for (int g_ = 0; g_ < 4; ++g_) { SGB(0x8, 4); SGB(0x100, 1); }
#define SGB_Q3  _Pragma("unroll") for (int g_ = 0; g_ < 4; ++g_) { SGB(0x8, 4); SGB(0x100, 2); }

    // ---- prologue: stage tiles 0 and 1 (FIFO: B0,A0,B1,A1); preload frags ----
    STAGE(Wb, nbase, 0, 0, 1, 0);
    STAGE(Wb, nbase, 0, 0, 1, 1);
    STAGE(Xb, rbase, 0, 0, 0, 0);
    STAGE(Xb, rbase, 0, 0, 0, 1);
    STAGE(Wb, nbase, 1, 1, 1, 0);
    STAGE(Wb, nbase, 1, 1, 1, 1);
    STAGE(Xb, rbase, 1, 1, 0, 0);
    STAGE(Xb, rbase, 1, 1, 0, 1);
    ASM_VMCNT8;   // tile0's 8 loads landed; tile1 (8) in flight
    SBAR; SFENCE;
    LOAD_B_TO(bm, 0, 0);
    LOAD_A(0, 0);

#define KBODY(TT, BUF) do {                                                     \
        const int kt2_ = ((TT) + 2) & (NKT - 1);                                \
        /* q0: MMA(mq0,bm); read ba<-B(t).nq1 (after, SGB interleaves) */       \
        PH_HEAD;                                                                \
        MMA_Q(0, 0, bm);                                                        \
        LOAD_B_TO(ba, BUF, 1);                                                  \
        SGB_Q0;                                                                 \
        PRIO0;                                                                  \
        /* q1: stage B(t+2); MMA(mq0,ba); read a<-A(t).mq1 */                   \
        PH_HEAD;                                                                \
        STAGE(Wb, nbase, kt2_, BUF, 1, 0);                                      \
        STAGE(Wb, nbase, kt2_, BUF, 1, 1);                                      \
        MMA_Q(0, 1, ba);                                                        \
        LOAD_A(BUF, 1);                                                         \
        SGB_Q1;                                                                 \
        PRIO0;                                                                  \
        /* q2: [vmcnt4 gate] stage A(t+2); MMA(mq1,bm); read bm<-B(t+1).nq0 */  \
        PH_HEADV;                                                               \
        STAGE(Xb, rbase, kt2_, BUF, 0, 0);                                      \
        STAGE(Xb, rbase, kt2_, BUF, 0, 1);                                      \
        MMA_Q_JK(1, 0, bm);                                                     \
        LOAD_B_TO(bm, (BUF) ^ 1, 0);                                            \
        SGB_Q2;                                                                 \
        PRIO0;                                                                  \
        /* q3: MMA(mq1,ba); read a<-A(t+1).mq0 */                               \
        PH_HEAD;                                                                \
        MMA_Q(1, 1, ba);                                                        \
        LOAD_A((BUF) ^ 1, 0);                                                   \
        SGB_Q3;                                                                 \
        PRIO0;                                                                  \
    } while (0)

    for (int t = 0; t < NKT; t += 2) {
        KBODY(t, 0);
        KBODY(t + 1, 1);
    }

    // ---- fused LSTM epilogue (reg-resident, zero-shuffle) ----
    const int s = (nblk * 4 + wn) * 16 + l15;
    float bg[4];
    #pragma unroll
    for (int jj = 0; jj < 4; ++jj)
        bg[jj] = biasR[nbase + wn * 64 + jj * 16 + l15];

    #pragma unroll
    for (int mi = 0; mi < 8; ++mi) {
        #pragma unroll
        for (int r = 0; r < 4; ++r) {
            const int row = rbase + wm * 128 + mi * 16 + krow * 4 + r;
            float fg = sigm(acc[mi][0][r] + bg[0]);
            float ig = sigm(acc[mi][1][r] + bg[1]);
            float og = sigm(acc[mi][2][r] + bg[2]);
            float gg = tanh_fast(acc[mi][3][r] + bg[3]);
            float oc = old_cell[(size_t)row * SD + s];
            float nc = fmaf(fg, oc, ig * gg);
            float nh = og * tanh_fast(nc);
            new_h[(size_t)row * SD + s]    = nh;
            new_cell[(size_t)row * SD + s] = nc;
        }
    }
}

extern "C" void kernel_launch(void* const* d_in, const int* in_sizes, int n_in,
                              void* d_out, int out_size, void* d_ws, size_t ws_size,
                              hipStream_t stream) {
    const float* input    = (const float*)d_in[0];
    const float* old_h    = (const float*)d_in[1];
    const float* old_cell = (const float*)d_in[2];
    const float* weights  = (const float*)d_in[3];
    const float* bias     = (const float*)d_in[4];

    unsigned short* Xb  = (unsigned short*)d_ws;                             // 16 MiB
    unsigned short* Wb  = (unsigned short*)((char*)d_ws + (size_t)16777216); // 16 MiB
    float*          bR  = (float*)((char*)d_ws + (size_t)33554432);          // 16 KiB

    float* out_h = (float*)d_out;
    float* out_c = out_h + (size_t)NB * SD;

    pack_kernel<<<2048, 256, 0, stream>>>(input, old_h, weights, bias, Xb, Wb, bR);
    lstm_gemm<<<(NB / BM) * (ND / BN), 512, 0, stream>>>(Xb, Wb, bR, old_cell,
                                                         out_h, out_c);
}

// Round 8
// 77.623 us; speedup vs baseline: 1.0299x; 1.0299x over previous
//
#include <hip/hip_runtime.h>
#include <stdint.h>

// Problem dims
#define NB   4096   // batch rows (M)
#define KD   2048   // IN + S   (K)
#define ND   4096   // 4*S      (N, reordered: n -> gate=(n>>4)&3, s=(n>>6)*16+(n&15))
#define SD   1024   // state size

// GEMM tile (256x256, 8 waves = 2M x 4N, deep-staged 4-phase pipeline)
#define BM   256
#define BN   256
#define BK   64
#define NKT  (KD / BK)   // 32 K-tiles

using f32x4  = __attribute__((ext_vector_type(4))) float;
using bf16x8 = __attribute__((ext_vector_type(8))) short;

typedef const __attribute__((address_space(1))) uint32_t* gas_u32;
typedef __attribute__((address_space(3))) uint32_t* las_u32;

__device__ __forceinline__ unsigned short f2bf(float f) {
    union { float f; uint32_t u; } c; c.f = f;
    uint32_t u = c.u;
    uint32_t r = (u + 0x7fffu + ((u >> 16) & 1u)) >> 16;  // RNE
    return (unsigned short)r;
}

__device__ __forceinline__ void async_load16(const void* gsrc, void* ldst) {
    __builtin_amdgcn_global_load_lds((gas_u32)gsrc, (las_u32)ldst, 16, 0, 0);
}

__device__ __forceinline__ float frcp(float x) { return __builtin_amdgcn_rcpf(x); }
__device__ __forceinline__ float sigm(float x) { return frcp(1.f + __expf(-x)); }
__device__ __forceinline__ float tanh_fast(float x) {
    return 1.f - 2.f * frcp(1.f + __expf(2.f * x));   // inf-safe
}

// ---------------------------------------------------------------------------
// Pack: fp32 -> bf16, X=[input|old_h]; W rows reordered so GEMM column
// n maps to weights row  gate*SD + (n>>6)*16 + (n&15),  gate=(n>>4)&3.
// ---------------------------------------------------------------------------
__global__ void pack_kernel(const float* __restrict__ input,
                            const float* __restrict__ old_h,
                            const float* __restrict__ weights,
                            const float* __restrict__ bias,
                            unsigned short* __restrict__ Xb,
                            unsigned short* __restrict__ Wb,
                            float* __restrict__ biasR) {
    const int XCH = NB * (KD / 4);
    const int WCH = ND * (KD / 4);
    const int BCH = ND / 4;
    const int total = XCH + WCH + BCH;
    for (int c = blockIdx.x * blockDim.x + threadIdx.x; c < total;
         c += gridDim.x * blockDim.x) {
        if (c < XCH) {
            int b  = c >> 9;
            int k  = (c & 511) << 2;
            const float* src = (k < 1024) ? (input + (size_t)b * 1024 + k)
                                          : (old_h + (size_t)b * 1024 + (k - 1024));
            float4 v = *reinterpret_cast<const float4*>(src);
            ushort4 o;
            o.x = f2bf(v.x); o.y = f2bf(v.y); o.z = f2bf(v.z); o.w = f2bf(v.w);
            *reinterpret_cast<ushort4*>(Xb + (size_t)b * KD + k) = o;
        } else if (c < XCH + WCH) {
            int cc = c - XCH;
            int n  = cc >> 9;
            int k  = (cc & 511) << 2;
            int srow = ((n >> 4) & 3) * SD + ((n >> 6) * 16 + (n & 15));
            float4 v = *reinterpret_cast<const float4*>(weights + (size_t)srow * KD + k);
            ushort4 o;
            o.x = f2bf(v.x); o.y = f2bf(v.y); o.z = f2bf(v.z); o.w = f2bf(v.w);
            *reinterpret_cast<ushort4*>(Wb + (size_t)n * KD + k) = o;
        } else {
            int n4 = (c - XCH - WCH) << 2;
            #pragma unroll
            for (int t = 0; t < 4; ++t) {
                int n = n4 + t;
                biasR[n] = bias[((n >> 4) & 3) * SD + ((n >> 6) * 16 + (n & 15))];
            }
        }
    }
}

// ---------------------------------------------------------------------------
// 256x256 GEMM + fused LSTM epilogue; 4 phases/K-tile, ONE barrier/phase,
// look-ahead-1 frag reads, DEEP staging (3-5 phase issue->gate lead).
// R8 change vs R5: NO sched_barrier(0) anywhere. The asm waitcnts keep
// "memory" clobbers (pins ds_read placement -> cross-wave region safety),
// but register-only MFMAs may float across them (rule-18 behavior), letting
// the compiler emit fine-grained lgkmcnt(N) so the LDS drain overlaps the
// MFMA cluster instead of fully serializing (R5-R7 profile: 621+656 cyc).
//   q0: [bar] MMA(mq0,bm) | read ba<-B(t).nq1          | stage: none
//   q1: [bar] MMA(mq0,ba) | read a <-A(t).mq1          | stage B(t+2).B0
//   q2: [lgkm+vmcnt2+bar] MMA(mq1,bm) | read bm<-B(t+1).nq0 | stage B(t+2).B1, A(t+2).A0
//   q3: [bar] MMA(mq1,ba) | read a <-A(t+1).mq0        | stage A(t+2).A1
// lgkmcnt(0) BEFORE s_barrier: all waves' reads of a region complete before
// any wave can pass the barrier and issue a stage that overwrites it.
// Region-hazard matrix: B(t) last read q0(t) -> staged q1(t)-end (1 bar apart);
// A(t) last read q1(t) -> staged q2/q3(t)-end. vmcnt(2) at q2 head: FIFO
// [B(t+1).B0 x2, B(t+1).B1+A(t+1).A0 x4, A(t+1).A1 x2, B(t+2).B0 x2]=10,
// drain 8 -> exactly tile t+1 landed before its first read (q2/q3).
// ---------------------------------------------------------------------------
#define SEG(DB, AB, HALF) (((((DB) * 2 + (AB)) * 2) + (HALF)) * 8192)

#define SBAR   __builtin_amdgcn_s_barrier()
#define ASM_LGKM0  asm volatile("s_waitcnt lgkmcnt(0)" ::: "memory")
#define ASM_VMCNT2 asm volatile("s_waitcnt vmcnt(2)" ::: "memory")
#define ASM_VMCNT8 asm volatile("s_waitcnt vmcnt(8)" ::: "memory")

__launch_bounds__(512, 2)
__global__ void lstm_gemm(const unsigned short* __restrict__ Xb,
                          const unsigned short* __restrict__ Wb,
                          const float* __restrict__ biasR,
                          const float* __restrict__ old_cell,
                          float* __restrict__ new_h,
                          float* __restrict__ new_cell) {
    __shared__ unsigned short lds[65536];   // 128 KiB

    const int tid  = threadIdx.x;
    const int lane = tid & 63;
    const int wid  = tid >> 6;       // 0..7
    const int wm   = wid >> 2;       // 0..1  (M half owner)
    const int wn   = wid & 3;        // 0..3  (N quarter owner)
    const int l15  = lane & 15;
    const int krow = lane >> 4;      // 0..3

    // XCD-aware bijective swizzle (256 blocks, 8 XCDs)
    const int wg    = blockIdx.x;
    const int swz   = (wg & 7) * 32 + (wg >> 3);
    const int mblk  = swz >> 4;
    const int nblk  = swz & 15;
    const int rbase = mblk * BM;
    const int nbase = nblk * BN;

    // staging per-thread constants: half-tile = 128 rows x 64 cols = 1024 chunks
    const int c0 = tid, c1 = tid + 512;
    const int srow0 = c0 >> 3, sk0 = ((c0 & 7) ^ (srow0 & 7)) * 8;
    const int srow1 = c1 >> 3, sk1 = ((c1 & 7) ^ (srow1 & 7)) * 8;

    f32x4  acc[8][4] = {};
    bf16x8 a[4][2];        // current A quadrant (renamed in place)
    bf16x8 bm[2][2];       // B wave-panel cols 0-31 (nq=0)
    bf16x8 ba[2][2];       // B wave-panel cols 32-63 (nq=1)

#define STAGE(PTR, TB, KT, DB, AB, HALF) do {                                   \
        async_load16((PTR) + (size_t)((TB) + (HALF) * 128 + srow0) * KD +       \
                         (KT) * BK + sk0,                                       \
                     lds + SEG(DB, AB, HALF) + c0 * 8);                         \
        async_load16((PTR) + (size_t)((TB) + (HALF) * 128 + srow1) * KD +       \
                         (KT) * BK + sk1,                                       \
                     lds + SEG(DB, AB, HALF) + c1 * 8);                         \
    } while (0)

#define LOAD_A(DB, MQ) do {                                                     \
        const unsigned short* base_ = lds + SEG(DB, 0, 0) + wm * 8192;          \
        _Pragma("unroll") for (int i_ = 0; i_ < 4; ++i_)                        \
        _Pragma("unroll") for (int kk_ = 0; kk_ < 2; ++kk_) {                   \
            int r_ = (MQ) * 64 + i_ * 16 + l15;                                 \
            int s_ = kk_ * 4 + krow;                                            \
            a[i_][kk_] = *reinterpret_cast<const bf16x8*>(                      \
                base_ + r_ * 64 + ((s_ ^ (r_ & 7)) * 8));                       \
        }                                                                       \
    } while (0)

#define LOAD_B_TO(DST, DB, NQ) do {                                             \
        const unsigned short* base_ = lds + SEG(DB, 1, 0) + (wn >> 1) * 8192;   \
        _Pragma("unroll") for (int j_ = 0; j_ < 2; ++j_)                        \
        _Pragma("unroll") for (int kk_ = 0; kk_ < 2; ++kk_) {                   \
            int r_ = (wn & 1) * 64 + ((NQ) * 2 + j_) * 16 + l15;                \
            int s_ = kk_ * 4 + krow;                                            \
            DST[j_][kk_] = *reinterpret_cast<const bf16x8*>(                    \
                base_ + r_ * 64 + ((s_ ^ (r_ & 7)) * 8));                       \
        }                                                                       \
    } while (0)

#define MMA_Q(MQ, NQH, BB) do {                                                 \
        _Pragma("unroll") for (int i_ = 0; i_ < 4; ++i_)                        \
        _Pragma("unroll") for (int j_ = 0; j_ < 2; ++j_)                        \
        _Pragma("unroll") for (int kk_ = 0; kk_ < 2; ++kk_)                     \
            acc[(MQ) * 4 + i_][(NQH) * 2 + j_] =                                \
                __builtin_amdgcn_mfma_f32_16x16x32_bf16(                        \
                    a[i_][kk_], BB[j_][kk_],                                    \
                    acc[(MQ) * 4 + i_][(NQH) * 2 + j_], 0, 0, 0);               \
    } while (0)

    // one barrier per phase; lgkm drained BEFORE barrier (cross-wave guarantee)
#define PH_HEAD   ASM_LGKM0; SBAR; __builtin_amdgcn_s_setprio(1)
#define PH_HEADV  ASM_LGKM0; ASM_VMCNT2; SBAR; __builtin_amdgcn_s_setprio(1)
#define PRIO0     __builtin_amdgcn_s_setprio(0)

    // ---- prologue: tiles 0,1 fully staged in steady-state FIFO order ----
    STAGE(Wb, nbase, 0, 0, 1, 0);
    STAGE(Wb, nbase, 0, 0, 1, 1);
    STAGE(Xb, rbase, 0, 0, 0, 0);
    STAGE(Xb, rbase, 0, 0, 0, 1);
    STAGE(Wb, nbase, 1, 1, 1, 0);
    STAGE(Wb, nbase, 1, 1, 1, 1);
    STAGE(Xb, rbase, 1, 1, 0, 0);
    STAGE(Xb, rbase, 1, 1, 0, 1);
    ASM_VMCNT8;   // tile0's 8 loads landed; tile1 (8) in flight
    SBAR;
    LOAD_B_TO(bm, 0, 0);
    LOAD_A(0, 0);

    // ---- main loop: one K-tile per KBODY; stages target tile t+2 ----
#define KBODY(TT, BUF) do {                                                     \
        const int kt2_ = ((TT) + 2) & (NKT - 1);                                \
        /* q0 */                                                                \
        PH_HEAD;  MMA_Q(0, 0, bm); LOAD_B_TO(ba, BUF, 1);       PRIO0;          \
        /* q1 */                                                                \
        PH_HEAD;  MMA_Q(0, 1, ba); LOAD_A(BUF, 1);              PRIO0;          \
        STAGE(Wb, nbase, kt2_, BUF, 1, 0);                                      \
        /* q2 */                                                                \
        PH_HEADV; MMA_Q(1, 0, bm); LOAD_B_TO(bm, (BUF) ^ 1, 0); PRIO0;          \
        STAGE(Wb, nbase, kt2_, BUF, 1, 1);                                      \
        STAGE(Xb, rbase, kt2_, BUF, 0, 0);                                      \
        /* q3 */                                                                \
        PH_HEAD;  MMA_Q(1, 1, ba); LOAD_A((BUF) ^ 1, 0);        PRIO0;          \
        STAGE(Xb, rbase, kt2_, BUF, 0, 1);                                      \
    } while (0)

    for (int t = 0; t < NKT; t += 2) {
        KBODY(t, 0);
        KBODY(t + 1, 1);
    }

    // ---- fused LSTM epilogue (reg-resident, zero-shuffle) ----
    const int s = (nblk * 4 + wn) * 16 + l15;
    float bg[4];
    #pragma unroll
    for (int jj = 0; jj < 4; ++jj)
        bg[jj] = biasR[nbase + wn * 64 + jj * 16 + l15];

    #pragma unroll
    for (int mi = 0; mi < 8; ++mi) {
        #pragma unroll
        for (int r = 0; r < 4; ++r) {
            const int row = rbase + wm * 128 + mi * 16 + krow * 4 + r;
            float fg = sigm(acc[mi][0][r] + bg[0]);
            float ig = sigm(acc[mi][1][r] + bg[1]);
            float og = sigm(acc[mi][2][r] + bg[2]);
            float gg = tanh_fast(acc[mi][3][r] + bg[3]);
            float oc = old_cell[(size_t)row * SD + s];
            float nc = fmaf(fg, oc, ig * gg);
            float nh = og * tanh_fast(nc);
            new_h[(size_t)row * SD + s]    = nh;
            new_cell[(size_t)row * SD + s] = nc;
        }
    }
}

extern "C" void kernel_launch(void* const* d_in, const int* in_sizes, int n_in,
                              void* d_out, int out_size, void* d_ws, size_t ws_size,
                              hipStream_t stream) {
    const float* input    = (const float*)d_in[0];
    const float* old_h    = (const float*)d_in[1];
    const float* old_cell = (const float*)d_in[2];
    const float* weights  = (const float*)d_in[3];
    const float* bias     = (const float*)d_in[4];

    unsigned short* Xb  = (unsigned short*)d_ws;                             // 16 MiB
    unsigned short* Wb  = (unsigned short*)((char*)d_ws + (size_t)16777216); // 16 MiB
    float*          bR  = (float*)((char*)d_ws + (size_t)33554432);          // 16 KiB

    float* out_h = (float*)d_out;
    float* out_c = out_h + (size_t)NB * SD;

    pack_kernel<<<2048, 256, 0, stream>>>(input, old_h, weights, bias, Xb, Wb, bR);
    lstm_gemm<<<(NB / BM) * (ND / BN), 512, 0, stream>>>(Xb, Wb, bR, old_cell,
                                                         out_h, out_c);
}